// Round 12
// baseline (196.249 us; speedup 1.0000x reference)
//
#include <hip/hip_runtime.h>
#include <hip/hip_fp16.h>
#include <math.h>

#define N_NODES 200000
#define N_EDGES 6400000
#define N_GRAPHS 128
#define NI4     (N_EDGES / 4)

// ---- coarse partition parameters ----
#define NBKC  128                 // coarse buckets
#define CBSZ  1568                // nodes per bucket: 128*1568 = 200704 >= 200000
#define CAP   51712               // slots per bucket (divisible by 4)
#define CHK   8000                // edges per partition block
#define CHK4  (CHK / 4)
#define PBLK  (N_EDGES / CHK)     // 800 partition blocks
#define NSUB8 8                   // sub-blocks per bucket

static __device__ __forceinline__ unsigned bc_of(unsigned n) { return n / (unsigned)CBSZ; }

// ============================================================
// kP1: single-pass LDS-staged partition into 128 coarse buckets.
// packed word = (src << 11) | dst_local
// ============================================================
__global__ void __launch_bounds__(512)
kP1_partition(const int* __restrict__ src, const int* __restrict__ dst,
              unsigned* __restrict__ gcur, unsigned* __restrict__ binned) {
    __shared__ unsigned cnt[NBKC];
    __shared__ unsigned ofs[NBKC];
    __shared__ unsigned cur[NBKC];
    __shared__ unsigned gofs[NBKC];
    __shared__ unsigned stage[CHK];
    const int tid = threadIdx.x;
    if (tid < NBKC) cnt[tid] = 0;
    __syncthreads();

    const int base4 = blockIdx.x * CHK4;
    const int4* s4 = (const int4*)src;
    const int4* d4 = (const int4*)dst;
    int4 sv[4], dv[4];
    bool ok[4];
    #pragma unroll
    for (int k = 0; k < 4; ++k) {
        int e = tid + k * 512;
        ok[k] = (e < CHK4);
        int ec = ok[k] ? e : 0;
        sv[k] = s4[base4 + ec];
        dv[k] = d4[base4 + ec];
    }
    #pragma unroll
    for (int k = 0; k < 4; ++k) {
        if (ok[k]) {
            atomicAdd(&cnt[bc_of((unsigned)dv[k].x)], 1u);
            atomicAdd(&cnt[bc_of((unsigned)dv[k].y)], 1u);
            atomicAdd(&cnt[bc_of((unsigned)dv[k].z)], 1u);
            atomicAdd(&cnt[bc_of((unsigned)dv[k].w)], 1u);
        }
    }
    __syncthreads();
    if (tid < 64) {
        unsigned v0 = cnt[tid];
        unsigned s0 = v0;
        for (int off = 1; off < 64; off <<= 1) {
            unsigned u = __shfl_up(s0, off);
            if (tid >= off) s0 += u;
        }
        unsigned tot0 = __shfl(s0, 63);
        unsigned v1 = cnt[64 + tid];
        unsigned s1 = v1;
        for (int off = 1; off < 64; off <<= 1) {
            unsigned u = __shfl_up(s1, off);
            if (tid >= off) s1 += u;
        }
        ofs[tid] = s0 - v0;
        ofs[64 + tid] = tot0 + s1 - v1;
    }
    __syncthreads();
    if (tid < NBKC) {
        gofs[tid] = atomicAdd(&gcur[tid], cnt[tid]);
        cur[tid] = ofs[tid];
    }
    __syncthreads();
    #pragma unroll
    for (int k = 0; k < 4; ++k) {
        if (ok[k]) {
            unsigned p;
            unsigned b0 = bc_of((unsigned)dv[k].x), l0 = (unsigned)dv[k].x - b0 * CBSZ;
            unsigned b1 = bc_of((unsigned)dv[k].y), l1 = (unsigned)dv[k].y - b1 * CBSZ;
            unsigned b2 = bc_of((unsigned)dv[k].z), l2 = (unsigned)dv[k].z - b2 * CBSZ;
            unsigned b3 = bc_of((unsigned)dv[k].w), l3 = (unsigned)dv[k].w - b3 * CBSZ;
            p = atomicAdd(&cur[b0], 1u); stage[p] = ((unsigned)sv[k].x << 11) | l0;
            p = atomicAdd(&cur[b1], 1u); stage[p] = ((unsigned)sv[k].y << 11) | l1;
            p = atomicAdd(&cur[b2], 1u); stage[p] = ((unsigned)sv[k].z << 11) | l2;
            p = atomicAdd(&cur[b3], 1u); stage[p] = ((unsigned)sv[k].w << 11) | l3;
        }
    }
    __syncthreads();
    const int wave = tid >> 6, lane = tid & 63;
    for (int b = wave; b < NBKC; b += 8) {
        unsigned o = ofs[b];
        unsigned end = (b < NBKC - 1) ? ofs[b + 1] : (unsigned)CHK;
        unsigned c = end - o;
        unsigned gb = gofs[b];
        if (gb >= (unsigned)CAP) continue;
        unsigned avail = (unsigned)CAP - gb;
        if (c > avail) c = avail;
        unsigned gbase = (unsigned)b * CAP + gb;
        for (unsigned i = lane; i < c; i += 64)
            binned[gbase + i] = stage[o + i];
    }
}

// sub-range helper: 4-aligned [s,e) split of [0,cnt)
static __device__ __forceinline__ void sub_range(unsigned cnt, int sub,
                                                 unsigned& s_, unsigned& e_) {
    unsigned per4 = (((cnt + NSUB8 - 1) / NSUB8) + 3u) & ~3u;
    unsigned s = (unsigned)sub * per4;
    if (s > cnt) s = cnt;
    unsigned e = s + per4;
    if (e > cnt) e = cnt;
    s_ = s; e_ = e;
}

// ============================================================
// kB: degree histogram per bucket.  Flat 4-batch loads (no loop).
// ============================================================
__global__ void __launch_bounds__(512)
kB_deg(const unsigned* __restrict__ binned, const unsigned* __restrict__ gcur,
       unsigned* __restrict__ part) {
    __shared__ unsigned bins[CBSZ];
    const int tid = threadIdx.x;
    for (int l = tid; l < CBSZ; l += 512) bins[l] = 0;
    __syncthreads();
    const int bkt = blockIdx.x >> 3, sub = blockIdx.x & 7;
    unsigned cnt = gcur[bkt];
    if (cnt > (unsigned)CAP) cnt = CAP;
    unsigned s, e;
    sub_range(cnt, sub, s, e);
    const unsigned base = (unsigned)bkt * CAP;
    const unsigned a0 = base + s, a1 = base + e;
    const uint4* b4 = (const uint4*)binned;
    const unsigned qb = a0 >> 2, qe = a1 >> 2;
    uint4 v[4]; bool ok[4];
    #pragma unroll
    for (int k = 0; k < 4; ++k) {
        unsigned q = qb + (unsigned)tid + (unsigned)k * 512u;
        ok[k] = (q < qe);
        v[k] = ok[k] ? b4[q] : make_uint4(0u, 0u, 0u, 0u);
    }
    #pragma unroll
    for (int k = 0; k < 4; ++k) {
        if (ok[k]) {
            atomicAdd(&bins[v[k].x & 2047u], 1u);
            atomicAdd(&bins[v[k].y & 2047u], 1u);
            atomicAdd(&bins[v[k].z & 2047u], 1u);
            atomicAdd(&bins[v[k].w & 2047u], 1u);
        }
    }
    unsigned t0 = a1 & ~3u;
    if (t0 >= a0 && tid < (int)(a1 - t0)) atomicAdd(&bins[binned[t0 + tid] & 2047u], 1u);
    __syncthreads();
    unsigned* dstp = part + (size_t)blockIdx.x * CBSZ;
    for (int l = tid; l < CBSZ; l += 512) dstp[l] = bins[l];
}

// kRedB: deg -> dinv; pairH = half2{x*dinv, dinv}; diF = dinv (f32)
__global__ void __launch_bounds__(512)
kRedB(const unsigned* __restrict__ part, const float* __restrict__ x,
      __half2* __restrict__ pairH, float* __restrict__ diF) {
    int n = blockIdx.x * 512 + threadIdx.x;
    if (n >= N_NODES) return;
    unsigned b = bc_of((unsigned)n);
    unsigned l = (unsigned)n - b * CBSZ;
    const unsigned* p = part + (size_t)(b * NSUB8) * CBSZ + l;
    unsigned d = 0;
    #pragma unroll
    for (int j = 0; j < NSUB8; ++j) d += p[(size_t)j * CBSZ];
    float di = rsqrtf((float)d + 1.0f);
    pairH[n] = __floats2half2_rn(x[n] * di, di);
    diF[n] = di;
}

// ============================================================
// kC: bins[dst] += {xd, di}[src] (one pk-f16 LDS atomic per edge).
// Flat 4-batch: load all uint4s -> 16 gathers in flight -> atomics.
// ============================================================
__global__ void __launch_bounds__(512)
kC_pass1(const unsigned* __restrict__ binned, const unsigned* __restrict__ gcur,
         const __half2* __restrict__ pairH, const float* __restrict__ diF,
         const int* __restrict__ batch,
         float* __restrict__ partF, float* __restrict__ gacc) {
    __shared__ __half2 binsP[CBSZ];
    __shared__ float gl[N_GRAPHS];
    const int tid = threadIdx.x;
    for (int l = tid; l < CBSZ; l += 512) binsP[l] = __floats2half2_rn(0.0f, 0.0f);
    if (tid < N_GRAPHS) gl[tid] = 0.0f;
    __syncthreads();
    const int bkt = blockIdx.x >> 3, sub = blockIdx.x & 7;
    unsigned cnt = gcur[bkt];
    if (cnt > (unsigned)CAP) cnt = CAP;
    unsigned s, e;
    sub_range(cnt, sub, s, e);
    const unsigned base = (unsigned)bkt * CAP;
    const unsigned a0 = base + s, a1 = base + e;
    const uint4* b4 = (const uint4*)binned;
    const unsigned qb = a0 >> 2, qe = a1 >> 2;

    uint4 v[4]; bool ok[4];
    #pragma unroll
    for (int k = 0; k < 4; ++k) {
        unsigned q = qb + (unsigned)tid + (unsigned)k * 512u;
        ok[k] = (q < qe);
        v[k] = ok[k] ? b4[q] : make_uint4(0u, 0u, 0u, 0u);
    }
    // issue all 16 gathers (index 0 is always a valid node)
    __half2 g[16];
    #pragma unroll
    for (int k = 0; k < 4; ++k) {
        g[4 * k + 0] = pairH[v[k].x >> 11];
        g[4 * k + 1] = pairH[v[k].y >> 11];
        g[4 * k + 2] = pairH[v[k].z >> 11];
        g[4 * k + 3] = pairH[v[k].w >> 11];
    }
    #pragma unroll
    for (int k = 0; k < 4; ++k) {
        if (ok[k]) {
            unsafeAtomicAdd(&binsP[v[k].x & 2047u], g[4 * k + 0]);
            unsafeAtomicAdd(&binsP[v[k].y & 2047u], g[4 * k + 1]);
            unsafeAtomicAdd(&binsP[v[k].z & 2047u], g[4 * k + 2]);
            unsafeAtomicAdd(&binsP[v[k].w & 2047u], g[4 * k + 3]);
        }
    }
    unsigned t0 = a1 & ~3u;
    if (t0 >= a0 && tid < (int)(a1 - t0)) {
        unsigned u = binned[t0 + tid];
        unsafeAtomicAdd(&binsP[u & 2047u], pairH[u >> 11]);
    }
    __syncthreads();
    float* dT = partF + (size_t)blockIdx.x * CBSZ;
    for (int l = tid; l < CBSZ; l += 512) {
        float2 p = __half22float2(binsP[l]);
        dT[l] = p.x;                      // t1 partial (f32 from here on)
        int node = bkt * CBSZ + l;
        if (node < N_NODES) {
            float val = diF[node] * p.y;  // s0 partial contribution
            if (val != 0.0f) atomicAdd(&gl[batch[node]], val);
        }
    }
    __syncthreads();
    if (tid < N_GRAPHS) {
        float val = gl[tid];
        if (val != 0.0f) atomicAdd(&gacc[N_GRAPHS + tid], val);
    }
}

// kRedC: agg1 = di*(t1+xd); adi = agg1*di; fold GS1 self + GS0 self + counts
__global__ void __launch_bounds__(512)
kRedC(const float* __restrict__ partF, const float* __restrict__ x,
      const float* __restrict__ diF, const int* __restrict__ batch,
      float* __restrict__ adi, float* __restrict__ gacc) {
    int n = blockIdx.x * 512 + threadIdx.x;
    bool valid = (n < N_NODES);
    float c1 = 0.0f, c0 = 0.0f, cc = 0.0f;
    int g = 0;
    if (valid) {
        unsigned b = bc_of((unsigned)n);
        unsigned l = (unsigned)n - b * CBSZ;
        const float* p = partF + (size_t)(b * NSUB8) * CBSZ + l;
        float t1 = 0.0f;
        #pragma unroll
        for (int j = 0; j < NSUB8; ++j) t1 += p[(size_t)j * CBSZ];
        float di = diF[n];
        float xd = x[n] * di;
        g = batch[n];
        float a = di * (t1 + xd);          // agg1 (self-loop folded)
        float ad = a * di;
        adi[n] = ad;
        c1 = di * ad;                      // GS1 self-loop
        c0 = di * di;                      // GS0 self-loop
        cc = 1.0f;
    }
    int tid = threadIdx.x;
    int g0 = __shfl(g, 0);
    bool uni = __all(!valid || (g == g0));
    if (uni) {
        for (int off = 32; off; off >>= 1) {
            c1 += __shfl_down(c1, off);
            c0 += __shfl_down(c0, off);
            cc += __shfl_down(cc, off);
        }
        if ((tid & 63) == 0) {
            atomicAdd(&gacc[g0], c1);
            atomicAdd(&gacc[N_GRAPHS + g0], c0);
            atomicAdd(&gacc[2 * N_GRAPHS + g0], cc);
        }
    } else if (valid) {
        atomicAdd(&gacc[g], c1);
        atomicAdd(&gacc[N_GRAPHS + g], c0);
        atomicAdd(&gacc[2 * N_GRAPHS + g], 1.0f);
    }
}

// ============================================================
// kD2: s1[dst] += adi[src].  Flat 4-batch, 16 gathers in flight.
// epilogue: LDS per-graph fold of di*s1_sub.
// ============================================================
__global__ void __launch_bounds__(512)
kD2_pass2(const unsigned* __restrict__ binned, const unsigned* __restrict__ gcur,
          const float* __restrict__ adi, const float* __restrict__ diF,
          const int* __restrict__ batch, float* __restrict__ gacc) {
    __shared__ float bins[CBSZ];
    __shared__ float gl[N_GRAPHS];
    const int tid = threadIdx.x;
    for (int l = tid; l < CBSZ; l += 512) bins[l] = 0.0f;
    if (tid < N_GRAPHS) gl[tid] = 0.0f;
    __syncthreads();
    const int bkt = blockIdx.x >> 3, sub = blockIdx.x & 7;
    unsigned cnt = gcur[bkt];
    if (cnt > (unsigned)CAP) cnt = CAP;
    unsigned s, e;
    sub_range(cnt, sub, s, e);
    const unsigned base = (unsigned)bkt * CAP;
    const unsigned a0 = base + s, a1 = base + e;
    const uint4* b4 = (const uint4*)binned;
    const unsigned qb = a0 >> 2, qe = a1 >> 2;

    uint4 v[4]; bool ok[4];
    #pragma unroll
    for (int k = 0; k < 4; ++k) {
        unsigned q = qb + (unsigned)tid + (unsigned)k * 512u;
        ok[k] = (q < qe);
        v[k] = ok[k] ? b4[q] : make_uint4(0u, 0u, 0u, 0u);
    }
    float g[16];
    #pragma unroll
    for (int k = 0; k < 4; ++k) {
        g[4 * k + 0] = adi[v[k].x >> 11];
        g[4 * k + 1] = adi[v[k].y >> 11];
        g[4 * k + 2] = adi[v[k].z >> 11];
        g[4 * k + 3] = adi[v[k].w >> 11];
    }
    #pragma unroll
    for (int k = 0; k < 4; ++k) {
        if (ok[k]) {
            atomicAdd(&bins[v[k].x & 2047u], g[4 * k + 0]);
            atomicAdd(&bins[v[k].y & 2047u], g[4 * k + 1]);
            atomicAdd(&bins[v[k].z & 2047u], g[4 * k + 2]);
            atomicAdd(&bins[v[k].w & 2047u], g[4 * k + 3]);
        }
    }
    unsigned t0 = a1 & ~3u;
    if (t0 >= a0 && tid < (int)(a1 - t0)) {
        unsigned u = binned[t0 + tid];
        atomicAdd(&bins[u & 2047u], adi[u >> 11]);
    }
    __syncthreads();
    for (int l = tid; l < CBSZ; l += 512) {
        int node = bkt * CBSZ + l;
        if (node < N_NODES) {
            float val = diF[node] * bins[l];
            if (val != 0.0f) atomicAdd(&gl[batch[node]], val);
        }
    }
    __syncthreads();
    if (tid < N_GRAPHS) {
        float val = gl[tid];
        if (val != 0.0f) atomicAdd(&gacc[tid], val);
    }
}

// ============================================================
// Final: pooled -> log_softmax
// ============================================================
__global__ void k_final(const float* __restrict__ gacc,
                        const float* __restrict__ W1, const float* __restrict__ b1,
                        const float* __restrict__ W2, const float* __restrict__ b2,
                        float* __restrict__ out) {
    int g = threadIdx.x;
    if (g >= N_GRAPHS) return;
    float GS1 = gacc[g];
    float GS0 = gacc[N_GRAPHS + g];
    float cnt = gacc[2 * N_GRAPHS + g];
    float denom = fmaxf(cnt, 1.0f);
    float p[8];
    for (int k = 0; k < 8; ++k) {
        float u = 0.0f, v = 0.0f;
        for (int c = 0; c < 32; ++c) {
            u += W1[c] * W2[c * 8 + k];
            v += b1[c] * W2[c * 8 + k];
        }
        p[k] = (u * GS1 + v * GS0 + cnt * b2[k]) / denom;
    }
    float m = p[0];
    for (int k = 1; k < 8; ++k) m = fmaxf(m, p[k]);
    float s = 0.0f;
    for (int k = 0; k < 8; ++k) s += expf(p[k] - m);
    float l = logf(s);
    for (int k = 0; k < 8; ++k) out[g * 8 + k] = p[k] - m - l;
}

// ============================================================
// Fallback: global-atomic pipeline (used only if ws too small)
// ============================================================
__global__ void k_deg(const int* __restrict__ dst, float* __restrict__ deg) {
    const int4* d4 = (const int4*)dst;
    for (int e = blockIdx.x * blockDim.x + threadIdx.x; e < NI4; e += gridDim.x * blockDim.x) {
        int4 d = d4[e];
        atomicAdd(&deg[d.x], 1.0f); atomicAdd(&deg[d.y], 1.0f);
        atomicAdd(&deg[d.z], 1.0f); atomicAdd(&deg[d.w], 1.0f);
    }
}
__global__ void k_dinv(const float* __restrict__ x, float* __restrict__ deg_dinv,
                       float* __restrict__ xd) {
    int i = blockIdx.x * blockDim.x + threadIdx.x;
    if (i < N_NODES) {
        float dinv = rsqrtf(deg_dinv[i] + 1.0f);
        deg_dinv[i] = dinv;
        xd[i] = x[i] * dinv;
    }
}
__global__ void k_pass1(const int* __restrict__ src, const int* __restrict__ dst,
                        const float* __restrict__ xd, float* __restrict__ t) {
    const int4* s4 = (const int4*)src;
    const int4* d4 = (const int4*)dst;
    for (int e = blockIdx.x * blockDim.x + threadIdx.x; e < NI4; e += gridDim.x * blockDim.x) {
        int4 s = s4[e]; int4 d = d4[e];
        atomicAdd(&t[d.x], xd[s.x]); atomicAdd(&t[d.y], xd[s.y]);
        atomicAdd(&t[d.z], xd[s.z]); atomicAdd(&t[d.w], xd[s.w]);
    }
}
__global__ void k_agg1(const float* __restrict__ dinv, const float* __restrict__ xd,
                       float* __restrict__ t, float2* __restrict__ pair) {
    int i = blockIdx.x * blockDim.x + threadIdx.x;
    if (i < N_NODES) {
        float di = dinv[i];
        float a = di * (t[i] + xd[i]);
        t[i] = a;
        pair[i] = make_float2(a * di, di);
    }
}
__global__ void k_pass2(const int* __restrict__ src, const int* __restrict__ dst,
                        const float2* __restrict__ pair,
                        float* __restrict__ s1, float* __restrict__ s0) {
    const int4* s4 = (const int4*)src;
    const int4* d4 = (const int4*)dst;
    for (int e = blockIdx.x * blockDim.x + threadIdx.x; e < NI4; e += gridDim.x * blockDim.x) {
        int4 s = s4[e]; int4 d = d4[e];
        float2 p0 = pair[s.x], p1 = pair[s.y], p2 = pair[s.z], p3 = pair[s.w];
        atomicAdd(&s1[d.x], p0.x); atomicAdd(&s0[d.x], p0.y);
        atomicAdd(&s1[d.y], p1.x); atomicAdd(&s0[d.y], p1.y);
        atomicAdd(&s1[d.z], p2.x); atomicAdd(&s0[d.z], p2.y);
        atomicAdd(&s1[d.w], p3.x); atomicAdd(&s0[d.w], p3.y);
    }
}
__global__ void k_node2(const float* __restrict__ dinv, const float* __restrict__ agg1,
                        const float* __restrict__ s1, const float* __restrict__ s0,
                        const int* __restrict__ batch, float* __restrict__ gacc) {
    int i = blockIdx.x * blockDim.x + threadIdx.x;
    float s1f = 0.0f, s0f = 0.0f; int g = 0;
    bool valid = (i < N_NODES);
    if (valid) {
        float di = dinv[i];
        s1f = di * (s1[i] + agg1[i] * di);
        s0f = di * (s0[i] + di);
        g = batch[i];
    }
    int g0 = __shfl(g, 0);
    bool uni = __all(valid && (g == g0));
    if (uni) {
        for (int off = 32; off; off >>= 1) {
            s1f += __shfl_down(s1f, off);
            s0f += __shfl_down(s0f, off);
        }
        if ((threadIdx.x & 63) == 0) {
            atomicAdd(&gacc[g0], s1f);
            atomicAdd(&gacc[N_GRAPHS + g0], s0f);
            atomicAdd(&gacc[2 * N_GRAPHS + g0], 64.0f);
        }
    } else if (valid) {
        atomicAdd(&gacc[g], s1f);
        atomicAdd(&gacc[N_GRAPHS + g], s0f);
        atomicAdd(&gacc[2 * N_GRAPHS + g], 1.0f);
    }
}

// ---------------- launch ----------------

extern "C" void kernel_launch(void* const* d_in, const int* in_sizes, int n_in,
                              void* d_out, int out_size, void* d_ws, size_t ws_size,
                              hipStream_t stream) {
    const float* x     = (const float*)d_in[0];
    const int*   edge  = (const int*)d_in[1];
    const int*   batch = (const int*)d_in[2];
    const float* W1    = (const float*)d_in[3];
    const float* b1    = (const float*)d_in[4];
    const float* W2    = (const float*)d_in[5];
    const float* b2    = (const float*)d_in[6];
    float* out = (float*)d_out;

    const int* src = edge;
    const int* dst = edge + N_EDGES;

    // workspace layout (u32 units) -- same total as R9-R11
    const size_t o_binned = 0;                                   // 6,619,136
    const size_t o_gcur   = o_binned + (size_t)NBKC * CAP;       // 128
    const size_t o_part   = o_gcur + NBKC;                       // 1,605,632
    const size_t o_pairH  = o_part + (size_t)NBKC * NSUB8 * CBSZ;// 200,000 (half2 = u32)
    const size_t o_diF    = o_pairH + N_NODES;                   // 200,000
    const size_t o_adi    = o_diF + N_NODES;                     // 200,000
    const size_t o_gacc   = o_adi + N_NODES;                     // 384
    const size_t need_u32 = o_gacc + 3 * N_GRAPHS;

    unsigned* ws_u = (unsigned*)d_ws;
    float*    ws_f = (float*)d_ws;

    if (ws_size >= need_u32 * 4) {
        unsigned* binned  = ws_u + o_binned;
        unsigned* gcur    = ws_u + o_gcur;
        unsigned* partU   = ws_u + o_part;
        float*    partF   = (float*)(ws_u + o_part);
        __half2*  pairH   = (__half2*)(ws_u + o_pairH);
        float*    diF     = ws_f + o_diF;
        float*    adi     = ws_f + o_adi;
        float*    gacc    = ws_f + o_gacc;

        hipMemsetAsync(gcur, 0, NBKC * sizeof(unsigned), stream);
        hipMemsetAsync(gacc, 0, 3 * N_GRAPHS * sizeof(float), stream);

        kP1_partition<<<PBLK, 512, 0, stream>>>(src, dst, gcur, binned);
        kB_deg       <<<NBKC * NSUB8, 512, 0, stream>>>(binned, gcur, partU);
        kRedB        <<<(N_NODES + 511) / 512, 512, 0, stream>>>(partU, x, pairH, diF);
        kC_pass1     <<<NBKC * NSUB8, 512, 0, stream>>>(binned, gcur, pairH, diF, batch, partF, gacc);
        kRedC        <<<(N_NODES + 511) / 512, 512, 0, stream>>>(partF, x, diF, batch, adi, gacc);
        kD2_pass2    <<<NBKC * NSUB8, 512, 0, stream>>>(binned, gcur, adi, diF, batch, gacc);
        k_final      <<<1, 128, 0, stream>>>(gacc, W1, b1, W2, b2, out);
    } else {
        float* dinv = ws_f;
        float* t    = ws_f + 1 * N_NODES;
        float* s1   = ws_f + 2 * N_NODES;
        float* s0   = ws_f + 3 * N_NODES;
        float* xd   = ws_f + 4 * N_NODES;
        float2* pair = (float2*)(ws_f + 6 * N_NODES);
        float* gacc = ws_f + 8 * N_NODES;

        hipMemsetAsync(ws_f, 0, (size_t)4 * N_NODES * sizeof(float), stream);
        hipMemsetAsync(gacc, 0, (size_t)3 * N_GRAPHS * sizeof(float), stream);

        const int EB = 2048, ET = 256;
        const int NB = (N_NODES + 255) / 256, NT = 256;

        k_deg  <<<EB, ET, 0, stream>>>(dst, dinv);
        k_dinv <<<NB, NT, 0, stream>>>(x, dinv, xd);
        k_pass1<<<EB, ET, 0, stream>>>(src, dst, xd, t);
        k_agg1 <<<NB, NT, 0, stream>>>(dinv, xd, t, pair);
        k_pass2<<<EB, ET, 0, stream>>>(src, dst, pair, s1, s0);
        k_node2<<<NB, NT, 0, stream>>>(dinv, t, s1, s0, batch, gacc);
        k_final<<<1, 128, 0, stream>>>(gacc, W1, b1, W2, b2, out);
    }
}

// Round 13
// 186.890 us; speedup vs baseline: 1.0501x; 1.0501x over previous
//
#include <hip/hip_runtime.h>
#include <hip/hip_fp16.h>
#include <math.h>

#define N_NODES 200000
#define N_EDGES 6400000
#define N_GRAPHS 128
#define NI4     (N_EDGES / 4)

// ---- coarse partition parameters ----
#define NBKC  128                 // coarse buckets
#define CBSZ  1568                // nodes per bucket: 128*1568 = 200704 >= 200000
#define CAP   51712               // slots per bucket (divisible by 4; mean 50000 +7.7 sigma)
#define PBLK  512                 // partition blocks: exactly 2 per CU, no tail
#define CHK   (N_EDGES / PBLK)    // 12500 edges per chunk
#define CHK4  (CHK / 4)           // 3125 int4 per chunk
#define NSUB8 8                   // sub-blocks per bucket

static __device__ __forceinline__ unsigned bc_of(unsigned n) { return n / (unsigned)CBSZ; }

// ============================================================
// kP1: single-pass LDS-staged partition into 128 coarse buckets.
// packed word = (src << 11) | dst_local
// ============================================================
__global__ void __launch_bounds__(512)
kP1_partition(const int* __restrict__ src, const int* __restrict__ dst,
              unsigned* __restrict__ gcur, unsigned* __restrict__ binned) {
    __shared__ unsigned cnt[NBKC];
    __shared__ unsigned ofs[NBKC];
    __shared__ unsigned cur[NBKC];
    __shared__ unsigned gofs[NBKC];
    __shared__ unsigned stage[CHK];   // 50 KB
    const int tid = threadIdx.x;
    if (tid < NBKC) cnt[tid] = 0;
    __syncthreads();

    const int base4 = blockIdx.x * CHK4;
    const int4* s4 = (const int4*)src;
    const int4* d4 = (const int4*)dst;
    int4 sv[7], dv[7];
    bool ok[7];
    #pragma unroll
    for (int k = 0; k < 7; ++k) {
        int e = tid + k * 512;
        ok[k] = (e < CHK4);
        int ec = ok[k] ? e : 0;
        sv[k] = s4[base4 + ec];
        dv[k] = d4[base4 + ec];
    }
    #pragma unroll
    for (int k = 0; k < 7; ++k) {
        if (ok[k]) {
            atomicAdd(&cnt[bc_of((unsigned)dv[k].x)], 1u);
            atomicAdd(&cnt[bc_of((unsigned)dv[k].y)], 1u);
            atomicAdd(&cnt[bc_of((unsigned)dv[k].z)], 1u);
            atomicAdd(&cnt[bc_of((unsigned)dv[k].w)], 1u);
        }
    }
    __syncthreads();
    if (tid < 64) {
        unsigned v0 = cnt[tid];
        unsigned s0 = v0;
        for (int off = 1; off < 64; off <<= 1) {
            unsigned u = __shfl_up(s0, off);
            if (tid >= off) s0 += u;
        }
        unsigned tot0 = __shfl(s0, 63);
        unsigned v1 = cnt[64 + tid];
        unsigned s1 = v1;
        for (int off = 1; off < 64; off <<= 1) {
            unsigned u = __shfl_up(s1, off);
            if (tid >= off) s1 += u;
        }
        ofs[tid] = s0 - v0;
        ofs[64 + tid] = tot0 + s1 - v1;
    }
    __syncthreads();
    if (tid < NBKC) {
        gofs[tid] = atomicAdd(&gcur[tid], cnt[tid]);
        cur[tid] = ofs[tid];
    }
    __syncthreads();
    #pragma unroll
    for (int k = 0; k < 7; ++k) {
        if (ok[k]) {
            unsigned p;
            unsigned b0 = bc_of((unsigned)dv[k].x), l0 = (unsigned)dv[k].x - b0 * CBSZ;
            unsigned b1 = bc_of((unsigned)dv[k].y), l1 = (unsigned)dv[k].y - b1 * CBSZ;
            unsigned b2 = bc_of((unsigned)dv[k].z), l2 = (unsigned)dv[k].z - b2 * CBSZ;
            unsigned b3 = bc_of((unsigned)dv[k].w), l3 = (unsigned)dv[k].w - b3 * CBSZ;
            p = atomicAdd(&cur[b0], 1u); stage[p] = ((unsigned)sv[k].x << 11) | l0;
            p = atomicAdd(&cur[b1], 1u); stage[p] = ((unsigned)sv[k].y << 11) | l1;
            p = atomicAdd(&cur[b2], 1u); stage[p] = ((unsigned)sv[k].z << 11) | l2;
            p = atomicAdd(&cur[b3], 1u); stage[p] = ((unsigned)sv[k].w << 11) | l3;
        }
    }
    __syncthreads();
    const int wave = tid >> 6, lane = tid & 63;
    for (int b = wave; b < NBKC; b += 8) {
        unsigned o = ofs[b];
        unsigned end = (b < NBKC - 1) ? ofs[b + 1] : (unsigned)CHK;
        unsigned c = end - o;
        unsigned gb = gofs[b];
        if (gb >= (unsigned)CAP) continue;
        unsigned avail = (unsigned)CAP - gb;
        if (c > avail) c = avail;
        unsigned gbase = (unsigned)b * CAP + gb;
        for (unsigned i = lane; i < c; i += 64)
            binned[gbase + i] = stage[o + i];
    }
}

// sub-range helper: 4-aligned [s,e) split of [0,cnt)
static __device__ __forceinline__ void sub_range(unsigned cnt, int sub,
                                                 unsigned& s_, unsigned& e_) {
    unsigned per4 = (((cnt + NSUB8 - 1) / NSUB8) + 3u) & ~3u;
    unsigned s = (unsigned)sub * per4;
    if (s > cnt) s = cnt;
    unsigned e = s + per4;
    if (e > cnt) e = cnt;
    s_ = s; e_ = e;
}

// ============================================================
// kB: degree histogram per bucket (uint4 loads, LDS atomic inc)  [R11 body]
// ============================================================
__global__ void __launch_bounds__(512)
kB_deg(const unsigned* __restrict__ binned, const unsigned* __restrict__ gcur,
       unsigned* __restrict__ part) {
    __shared__ unsigned bins[CBSZ];
    const int tid = threadIdx.x;
    for (int l = tid; l < CBSZ; l += 512) bins[l] = 0;
    __syncthreads();
    const int bkt = blockIdx.x >> 3, sub = blockIdx.x & 7;
    unsigned cnt = gcur[bkt];
    if (cnt > (unsigned)CAP) cnt = CAP;
    unsigned s, e;
    sub_range(cnt, sub, s, e);
    const unsigned base = (unsigned)bkt * CAP;
    const unsigned a0 = base + s, a1 = base + e;
    const uint4* b4 = (const uint4*)binned;
    for (unsigned q = (a0 >> 2) + tid; q < (a1 >> 2); q += 512) {
        uint4 v = b4[q];
        atomicAdd(&bins[v.x & 2047u], 1u);
        atomicAdd(&bins[v.y & 2047u], 1u);
        atomicAdd(&bins[v.z & 2047u], 1u);
        atomicAdd(&bins[v.w & 2047u], 1u);
    }
    unsigned t0 = a1 & ~3u;
    if (t0 >= a0 && tid < (int)(a1 - t0)) atomicAdd(&bins[binned[t0 + tid] & 2047u], 1u);
    __syncthreads();
    unsigned* dstp = part + (size_t)blockIdx.x * CBSZ;
    for (int l = tid; l < CBSZ; l += 512) dstp[l] = bins[l];
}

// kRedB: deg -> dinv; pairH = half2{x*dinv, dinv}; diF = dinv (f32)
__global__ void __launch_bounds__(512)
kRedB(const unsigned* __restrict__ part, const float* __restrict__ x,
      __half2* __restrict__ pairH, float* __restrict__ diF) {
    int n = blockIdx.x * 512 + threadIdx.x;
    if (n >= N_NODES) return;
    unsigned b = bc_of((unsigned)n);
    unsigned l = (unsigned)n - b * CBSZ;
    const unsigned* p = part + (size_t)(b * NSUB8) * CBSZ + l;
    unsigned d = 0;
    #pragma unroll
    for (int j = 0; j < NSUB8; ++j) d += p[(size_t)j * CBSZ];
    float di = rsqrtf((float)d + 1.0f);
    pairH[n] = __floats2half2_rn(x[n] * di, di);
    diF[n] = di;
}

// ============================================================
// kC: one packed-f16 LDS atomic per edge: bins[dst] += {xd, di}[src]
// (ds_pk_add_f16 via unsafeAtomicAdd).  [R11 body]
// ============================================================
__global__ void __launch_bounds__(512)
kC_pass1(const unsigned* __restrict__ binned, const unsigned* __restrict__ gcur,
         const __half2* __restrict__ pairH, const float* __restrict__ diF,
         const int* __restrict__ batch,
         float* __restrict__ partF, float* __restrict__ gacc) {
    __shared__ __half2 binsP[CBSZ];
    __shared__ float gl[N_GRAPHS];
    const int tid = threadIdx.x;
    for (int l = tid; l < CBSZ; l += 512) binsP[l] = __floats2half2_rn(0.0f, 0.0f);
    if (tid < N_GRAPHS) gl[tid] = 0.0f;
    __syncthreads();
    const int bkt = blockIdx.x >> 3, sub = blockIdx.x & 7;
    unsigned cnt = gcur[bkt];
    if (cnt > (unsigned)CAP) cnt = CAP;
    unsigned s, e;
    sub_range(cnt, sub, s, e);
    const unsigned base = (unsigned)bkt * CAP;
    const unsigned a0 = base + s, a1 = base + e;
    const uint4* b4 = (const uint4*)binned;
    const unsigned qe = a1 >> 2;
    for (unsigned q = (a0 >> 2) + tid; q < qe; q += 1024) {
        uint4 v = b4[q];
        bool has2 = (q + 512u) < qe;
        uint4 w = has2 ? b4[q + 512u] : v;
        __half2 p0 = pairH[v.x >> 11];
        __half2 p1 = pairH[v.y >> 11];
        __half2 p2 = pairH[v.z >> 11];
        __half2 p3 = pairH[v.w >> 11];
        __half2 r0 = pairH[w.x >> 11];
        __half2 r1 = pairH[w.y >> 11];
        __half2 r2 = pairH[w.z >> 11];
        __half2 r3 = pairH[w.w >> 11];
        unsafeAtomicAdd(&binsP[v.x & 2047u], p0);
        unsafeAtomicAdd(&binsP[v.y & 2047u], p1);
        unsafeAtomicAdd(&binsP[v.z & 2047u], p2);
        unsafeAtomicAdd(&binsP[v.w & 2047u], p3);
        if (has2) {
            unsafeAtomicAdd(&binsP[w.x & 2047u], r0);
            unsafeAtomicAdd(&binsP[w.y & 2047u], r1);
            unsafeAtomicAdd(&binsP[w.z & 2047u], r2);
            unsafeAtomicAdd(&binsP[w.w & 2047u], r3);
        }
    }
    unsigned t0 = a1 & ~3u;
    if (t0 >= a0 && tid < (int)(a1 - t0)) {
        unsigned v = binned[t0 + tid];
        unsafeAtomicAdd(&binsP[v & 2047u], pairH[v >> 11]);
    }
    __syncthreads();
    float* dT = partF + (size_t)blockIdx.x * CBSZ;
    for (int l = tid; l < CBSZ; l += 512) {
        float2 p = __half22float2(binsP[l]);
        dT[l] = p.x;                      // t1 partial (f32 from here on)
        int node = bkt * CBSZ + l;
        if (node < N_NODES) {
            float val = diF[node] * p.y;  // s0 partial contribution
            if (val != 0.0f) atomicAdd(&gl[batch[node]], val);
        }
    }
    __syncthreads();
    if (tid < N_GRAPHS) {
        float val = gl[tid];
        if (val != 0.0f) atomicAdd(&gacc[N_GRAPHS + tid], val);
    }
}

// kRedC: agg1 = di*(t1+xd); adi = agg1*di; fold GS1 self + GS0 self + counts
__global__ void __launch_bounds__(512)
kRedC(const float* __restrict__ partF, const float* __restrict__ x,
      const float* __restrict__ diF, const int* __restrict__ batch,
      float* __restrict__ adi, float* __restrict__ gacc) {
    int n = blockIdx.x * 512 + threadIdx.x;
    bool valid = (n < N_NODES);
    float c1 = 0.0f, c0 = 0.0f, cc = 0.0f;
    int g = 0;
    if (valid) {
        unsigned b = bc_of((unsigned)n);
        unsigned l = (unsigned)n - b * CBSZ;
        const float* p = partF + (size_t)(b * NSUB8) * CBSZ + l;
        float t1 = 0.0f;
        #pragma unroll
        for (int j = 0; j < NSUB8; ++j) t1 += p[(size_t)j * CBSZ];
        float di = diF[n];
        float xd = x[n] * di;
        g = batch[n];
        float a = di * (t1 + xd);          // agg1 (self-loop folded)
        float ad = a * di;
        adi[n] = ad;
        c1 = di * ad;                      // GS1 self-loop
        c0 = di * di;                      // GS0 self-loop
        cc = 1.0f;
    }
    int tid = threadIdx.x;
    int g0 = __shfl(g, 0);
    bool uni = __all(!valid || (g == g0));
    if (uni) {
        for (int off = 32; off; off >>= 1) {
            c1 += __shfl_down(c1, off);
            c0 += __shfl_down(c0, off);
            cc += __shfl_down(cc, off);
        }
        if ((tid & 63) == 0) {
            atomicAdd(&gacc[g0], c1);
            atomicAdd(&gacc[N_GRAPHS + g0], c0);
            atomicAdd(&gacc[2 * N_GRAPHS + g0], cc);
        }
    } else if (valid) {
        atomicAdd(&gacc[g], c1);
        atomicAdd(&gacc[N_GRAPHS + g], c0);
        atomicAdd(&gacc[2 * N_GRAPHS + g], 1.0f);
    }
}

// ============================================================
// kD2: s1[dst] += adi[src]; 2x unroll; epilogue LDS per-graph fold  [R11 body]
// ============================================================
__global__ void __launch_bounds__(512)
kD2_pass2(const unsigned* __restrict__ binned, const unsigned* __restrict__ gcur,
          const float* __restrict__ adi, const float* __restrict__ diF,
          const int* __restrict__ batch, float* __restrict__ gacc) {
    __shared__ float bins[CBSZ];
    __shared__ float gl[N_GRAPHS];
    const int tid = threadIdx.x;
    for (int l = tid; l < CBSZ; l += 512) bins[l] = 0.0f;
    if (tid < N_GRAPHS) gl[tid] = 0.0f;
    __syncthreads();
    const int bkt = blockIdx.x >> 3, sub = blockIdx.x & 7;
    unsigned cnt = gcur[bkt];
    if (cnt > (unsigned)CAP) cnt = CAP;
    unsigned s, e;
    sub_range(cnt, sub, s, e);
    const unsigned base = (unsigned)bkt * CAP;
    const unsigned a0 = base + s, a1 = base + e;
    const uint4* b4 = (const uint4*)binned;
    const unsigned qe = a1 >> 2;
    for (unsigned q = (a0 >> 2) + tid; q < qe; q += 1024) {
        uint4 v = b4[q];
        bool has2 = (q + 512u) < qe;
        uint4 w = has2 ? b4[q + 512u] : v;
        float g0 = adi[v.x >> 11], g1 = adi[v.y >> 11];
        float g2 = adi[v.z >> 11], g3 = adi[v.w >> 11];
        float h0 = adi[w.x >> 11], h1 = adi[w.y >> 11];
        float h2 = adi[w.z >> 11], h3 = adi[w.w >> 11];
        atomicAdd(&bins[v.x & 2047u], g0);
        atomicAdd(&bins[v.y & 2047u], g1);
        atomicAdd(&bins[v.z & 2047u], g2);
        atomicAdd(&bins[v.w & 2047u], g3);
        if (has2) {
            atomicAdd(&bins[w.x & 2047u], h0);
            atomicAdd(&bins[w.y & 2047u], h1);
            atomicAdd(&bins[w.z & 2047u], h2);
            atomicAdd(&bins[w.w & 2047u], h3);
        }
    }
    unsigned t0 = a1 & ~3u;
    if (t0 >= a0 && tid < (int)(a1 - t0)) {
        unsigned v = binned[t0 + tid];
        atomicAdd(&bins[v & 2047u], adi[v >> 11]);
    }
    __syncthreads();
    for (int l = tid; l < CBSZ; l += 512) {
        int node = bkt * CBSZ + l;
        if (node < N_NODES) {
            float val = diF[node] * bins[l];
            if (val != 0.0f) atomicAdd(&gl[batch[node]], val);
        }
    }
    __syncthreads();
    if (tid < N_GRAPHS) {
        float val = gl[tid];
        if (val != 0.0f) atomicAdd(&gacc[tid], val);
    }
}

// ============================================================
// Final: pooled -> log_softmax
// ============================================================
__global__ void k_final(const float* __restrict__ gacc,
                        const float* __restrict__ W1, const float* __restrict__ b1,
                        const float* __restrict__ W2, const float* __restrict__ b2,
                        float* __restrict__ out) {
    int g = threadIdx.x;
    if (g >= N_GRAPHS) return;
    float GS1 = gacc[g];
    float GS0 = gacc[N_GRAPHS + g];
    float cnt = gacc[2 * N_GRAPHS + g];
    float denom = fmaxf(cnt, 1.0f);
    float p[8];
    for (int k = 0; k < 8; ++k) {
        float u = 0.0f, v = 0.0f;
        for (int c = 0; c < 32; ++c) {
            u += W1[c] * W2[c * 8 + k];
            v += b1[c] * W2[c * 8 + k];
        }
        p[k] = (u * GS1 + v * GS0 + cnt * b2[k]) / denom;
    }
    float m = p[0];
    for (int k = 1; k < 8; ++k) m = fmaxf(m, p[k]);
    float s = 0.0f;
    for (int k = 0; k < 8; ++k) s += expf(p[k] - m);
    float l = logf(s);
    for (int k = 0; k < 8; ++k) out[g * 8 + k] = p[k] - m - l;
}

// ============================================================
// Fallback: global-atomic pipeline (used only if ws too small)
// ============================================================
__global__ void k_deg(const int* __restrict__ dst, float* __restrict__ deg) {
    const int4* d4 = (const int4*)dst;
    for (int e = blockIdx.x * blockDim.x + threadIdx.x; e < NI4; e += gridDim.x * blockDim.x) {
        int4 d = d4[e];
        atomicAdd(&deg[d.x], 1.0f); atomicAdd(&deg[d.y], 1.0f);
        atomicAdd(&deg[d.z], 1.0f); atomicAdd(&deg[d.w], 1.0f);
    }
}
__global__ void k_dinv(const float* __restrict__ x, float* __restrict__ deg_dinv,
                       float* __restrict__ xd) {
    int i = blockIdx.x * blockDim.x + threadIdx.x;
    if (i < N_NODES) {
        float dinv = rsqrtf(deg_dinv[i] + 1.0f);
        deg_dinv[i] = dinv;
        xd[i] = x[i] * dinv;
    }
}
__global__ void k_pass1(const int* __restrict__ src, const int* __restrict__ dst,
                        const float* __restrict__ xd, float* __restrict__ t) {
    const int4* s4 = (const int4*)src;
    const int4* d4 = (const int4*)dst;
    for (int e = blockIdx.x * blockDim.x + threadIdx.x; e < NI4; e += gridDim.x * blockDim.x) {
        int4 s = s4[e]; int4 d = d4[e];
        atomicAdd(&t[d.x], xd[s.x]); atomicAdd(&t[d.y], xd[s.y]);
        atomicAdd(&t[d.z], xd[s.z]); atomicAdd(&t[d.w], xd[s.w]);
    }
}
__global__ void k_agg1(const float* __restrict__ dinv, const float* __restrict__ xd,
                       float* __restrict__ t, float2* __restrict__ pair) {
    int i = blockIdx.x * blockDim.x + threadIdx.x;
    if (i < N_NODES) {
        float di = dinv[i];
        float a = di * (t[i] + xd[i]);
        t[i] = a;
        pair[i] = make_float2(a * di, di);
    }
}
__global__ void k_pass2(const int* __restrict__ src, const int* __restrict__ dst,
                        const float2* __restrict__ pair,
                        float* __restrict__ s1, float* __restrict__ s0) {
    const int4* s4 = (const int4*)src;
    const int4* d4 = (const int4*)dst;
    for (int e = blockIdx.x * blockDim.x + threadIdx.x; e < NI4; e += gridDim.x * blockDim.x) {
        int4 s = s4[e]; int4 d = d4[e];
        float2 p0 = pair[s.x], p1 = pair[s.y], p2 = pair[s.z], p3 = pair[s.w];
        atomicAdd(&s1[d.x], p0.x); atomicAdd(&s0[d.x], p0.y);
        atomicAdd(&s1[d.y], p1.x); atomicAdd(&s0[d.y], p1.y);
        atomicAdd(&s1[d.z], p2.x); atomicAdd(&s0[d.z], p2.y);
        atomicAdd(&s1[d.w], p3.x); atomicAdd(&s0[d.w], p3.y);
    }
}
__global__ void k_node2(const float* __restrict__ dinv, const float* __restrict__ agg1,
                        const float* __restrict__ s1, const float* __restrict__ s0,
                        const int* __restrict__ batch, float* __restrict__ gacc) {
    int i = blockIdx.x * blockDim.x + threadIdx.x;
    float s1f = 0.0f, s0f = 0.0f; int g = 0;
    bool valid = (i < N_NODES);
    if (valid) {
        float di = dinv[i];
        s1f = di * (s1[i] + agg1[i] * di);
        s0f = di * (s0[i] + di);
        g = batch[i];
    }
    int g0 = __shfl(g, 0);
    bool uni = __all(valid && (g == g0));
    if (uni) {
        for (int off = 32; off; off >>= 1) {
            s1f += __shfl_down(s1f, off);
            s0f += __shfl_down(s0f, off);
        }
        if ((threadIdx.x & 63) == 0) {
            atomicAdd(&gacc[g0], s1f);
            atomicAdd(&gacc[N_GRAPHS + g0], s0f);
            atomicAdd(&gacc[2 * N_GRAPHS + g0], 64.0f);
        }
    } else if (valid) {
        atomicAdd(&gacc[g], s1f);
        atomicAdd(&gacc[N_GRAPHS + g], s0f);
        atomicAdd(&gacc[2 * N_GRAPHS + g], 1.0f);
    }
}

// ---------------- launch ----------------

extern "C" void kernel_launch(void* const* d_in, const int* in_sizes, int n_in,
                              void* d_out, int out_size, void* d_ws, size_t ws_size,
                              hipStream_t stream) {
    const float* x     = (const float*)d_in[0];
    const int*   edge  = (const int*)d_in[1];
    const int*   batch = (const int*)d_in[2];
    const float* W1    = (const float*)d_in[3];
    const float* b1    = (const float*)d_in[4];
    const float* W2    = (const float*)d_in[5];
    const float* b2    = (const float*)d_in[6];
    float* out = (float*)d_out;

    const int* src = edge;
    const int* dst = edge + N_EDGES;

    // workspace layout (u32 units) -- same total as R9-R12
    const size_t o_binned = 0;                                   // 6,619,136
    const size_t o_gcur   = o_binned + (size_t)NBKC * CAP;       // 128
    const size_t o_part   = o_gcur + NBKC;                       // 1,605,632
    const size_t o_pairH  = o_part + (size_t)NBKC * NSUB8 * CBSZ;// 200,000 (half2 = u32)
    const size_t o_diF    = o_pairH + N_NODES;                   // 200,000
    const size_t o_adi    = o_diF + N_NODES;                     // 200,000
    const size_t o_gacc   = o_adi + N_NODES;                     // 384
    const size_t need_u32 = o_gacc + 3 * N_GRAPHS;

    unsigned* ws_u = (unsigned*)d_ws;
    float*    ws_f = (float*)d_ws;

    if (ws_size >= need_u32 * 4) {
        unsigned* binned  = ws_u + o_binned;
        unsigned* gcur    = ws_u + o_gcur;
        unsigned* partU   = ws_u + o_part;
        float*    partF   = (float*)(ws_u + o_part);
        __half2*  pairH   = (__half2*)(ws_u + o_pairH);
        float*    diF     = ws_f + o_diF;
        float*    adi     = ws_f + o_adi;
        float*    gacc    = ws_f + o_gacc;

        hipMemsetAsync(gcur, 0, NBKC * sizeof(unsigned), stream);
        hipMemsetAsync(gacc, 0, 3 * N_GRAPHS * sizeof(float), stream);

        kP1_partition<<<PBLK, 512, 0, stream>>>(src, dst, gcur, binned);
        kB_deg       <<<NBKC * NSUB8, 512, 0, stream>>>(binned, gcur, partU);
        kRedB        <<<(N_NODES + 511) / 512, 512, 0, stream>>>(partU, x, pairH, diF);
        kC_pass1     <<<NBKC * NSUB8, 512, 0, stream>>>(binned, gcur, pairH, diF, batch, partF, gacc);
        kRedC        <<<(N_NODES + 511) / 512, 512, 0, stream>>>(partF, x, diF, batch, adi, gacc);
        kD2_pass2    <<<NBKC * NSUB8, 512, 0, stream>>>(binned, gcur, adi, diF, batch, gacc);
        k_final      <<<1, 128, 0, stream>>>(gacc, W1, b1, W2, b2, out);
    } else {
        float* dinv = ws_f;
        float* t    = ws_f + 1 * N_NODES;
        float* s1   = ws_f + 2 * N_NODES;
        float* s0   = ws_f + 3 * N_NODES;
        float* xd   = ws_f + 4 * N_NODES;
        float2* pair = (float2*)(ws_f + 6 * N_NODES);
        float* gacc = ws_f + 8 * N_NODES;

        hipMemsetAsync(ws_f, 0, (size_t)4 * N_NODES * sizeof(float), stream);
        hipMemsetAsync(gacc, 0, (size_t)3 * N_GRAPHS * sizeof(float), stream);

        const int EB = 2048, ET = 256;
        const int NB = (N_NODES + 255) / 256, NT = 256;

        k_deg  <<<EB, ET, 0, stream>>>(dst, dinv);
        k_dinv <<<NB, NT, 0, stream>>>(x, dinv, xd);
        k_pass1<<<EB, ET, 0, stream>>>(src, dst, xd, t);
        k_agg1 <<<NB, NT, 0, stream>>>(dinv, xd, t, pair);
        k_pass2<<<EB, ET, 0, stream>>>(src, dst, pair, s1, s0);
        k_node2<<<NB, NT, 0, stream>>>(dinv, t, s1, s0, batch, gacc);
        k_final<<<1, 128, 0, stream>>>(gacc, W1, b1, W2, b2, out);
    }
}